// Round 13
// baseline (3231.314 us; speedup 1.0000x reference)
//
#include <hip/hip_runtime.h>

// ReservoirLayer: S0 = pad(x,[2048,4096]); 16x: S = leaky_relu(S @ W, 0.1)
// fp32-emulation via fp16 hi/lo split (fp16x3): acc = Sh@Wh + Sl@Wh + Sh@Wl.
// R15: amortization attack. Evidence: period/K-tile ~3330cyc vs MFMA-pipe
//     1862 across ALL of R3..R14; null levers: counted vmcnt, LDS volume,
//     occupancy, conflicts, shape. Remaining knobs: MFMA-per-barrier and
//     MFMA-per-read. Geometry: BM=256 x BN=128, 8 waves (128x32/wave),
//     grid 256 = 1 block/CU. Per tile/wave: 48 MFMA / 20 ds_read / ONE
//     barrier. THREE LDS buffers (144KB; gfx950 static >64KB is
//     guide-validated at 128KB/m201 and 160KB/HK-attn) eliminate
//     write-after-read: stage(it+2) -> buffer read at it-1 (drained before
//     this tile's single barrier). vmcnt(6) counted (12 in flight steady,
//     never 0 mid-loop); no lgkm drain -> compiler interleaves reads under
//     MFMAs. Same fp16x3 numerics.
// R16 == R15 resubmission: round-12 failure was container-level (no compile/
//     pytest output), same mode as R8 which passed on identical resubmit.
//     Deadlock audit: uniform barriers, counted vmcnt can't over-wait,
//     3-buffer rotation WAR-safe, VGPR within (512,2) budget.

#define BATCH 2048
#define NDIM  4096
#define INDIM 512
#define BM 256
#define BN 128
#define BK 32

typedef _Float16 f16x8 __attribute__((ext_vector_type(8)));
typedef float    f32x4 __attribute__((ext_vector_type(4)));

__device__ __forceinline__ void async16(const void* gsrc, void* ldst) {
  const __attribute__((address_space(1))) unsigned int* g =
      (const __attribute__((address_space(1))) unsigned int*)gsrc;
  __attribute__((address_space(3))) unsigned int* l =
      (__attribute__((address_space(3))) unsigned int*)ldst;
  __builtin_amdgcn_global_load_lds(g, l, 16, 0, 0);
}

#define WAITV6() do { asm volatile("s_waitcnt vmcnt(6)" ::: "memory"); \
                      __builtin_amdgcn_sched_barrier(0); } while (0)
#define WAITV0() do { asm volatile("s_waitcnt vmcnt(0)" ::: "memory"); \
                      __builtin_amdgcn_sched_barrier(0); } while (0)
#define SBAR()   __builtin_amdgcn_s_barrier()

// ---------------- prep: split+pad x into S_hi/S_lo ----------------
__global__ void prep_x(const float* __restrict__ x,
                       _Float16* __restrict__ Sh, _Float16* __restrict__ Sl) {
  size_t i = (size_t)blockIdx.x * 256 + threadIdx.x;  // over BATCH*NDIM
  int b = (int)(i >> 12);
  int n = (int)(i & (NDIM - 1));
  float v = (n < INDIM) ? x[(size_t)b * INDIM + n] : 0.0f;
  _Float16 h = (_Float16)v;
  Sh[i] = h;
  Sl[i] = (_Float16)(v - (float)h);
}

// ---------------- prep: transpose + scale(256) + split W ----------------
__global__ void prep_w(const float* __restrict__ W,
                       _Float16* __restrict__ Wth, _Float16* __restrict__ Wtl) {
  __shared__ float tile[32][33];
  int k0 = blockIdx.y * 32, n0 = blockIdx.x * 32;
  int tx = threadIdx.x, ty = threadIdx.y;  // 32 x 8
  for (int r = 0; r < 4; r++) {
    int k = k0 + ty + r * 8;
    tile[ty + r * 8][tx] = W[(size_t)k * NDIM + n0 + tx];
  }
  __syncthreads();
  for (int r = 0; r < 4; r++) {
    int n = n0 + ty + r * 8;
    float v = tile[tx][ty + r * 8] * 256.0f;
    _Float16 h = (_Float16)v;
    Wth[(size_t)n * NDIM + k0 + tx] = h;
    Wtl[(size_t)n * NDIM + k0 + tx] = (_Float16)(v - (float)h);
  }
}

// frag reads from buffer p (runtime 0/1/2)
#define READF(p)                                       \
  do {                                                 \
    const _Float16* bAh = &sAh[p][0];                  \
    const _Float16* bAl = &sAl[p][0];                  \
    const _Float16* bBh = &sBh[p][0];                  \
    const _Float16* bBl = &sBl[p][0];                  \
    _Pragma("unroll") for (int i = 0; i < 8; i++) {    \
      af[i] = *(const f16x8*)&bAh[oA[i]];              \
      lf[i] = *(const f16x8*)&bAl[oA[i]];              \
    }                                                  \
    _Pragma("unroll") for (int j = 0; j < 2; j++) {    \
      bf[j] = *(const f16x8*)&bBh[oB[j]];              \
      mf[j] = *(const f16x8*)&bBl[oB[j]];              \
    }                                                  \
  } while (0)

// term-major: same-acc reuse distance 16; per-acc order AB -> LB -> AM
#define MFMAS()                                                                     \
  do {                                                                              \
    _Pragma("unroll") for (int j = 0; j < 2; j++)                                   \
    _Pragma("unroll") for (int i = 0; i < 8; i++)                                   \
      acc[i][j] = __builtin_amdgcn_mfma_f32_16x16x32_f16(af[i], bf[j], acc[i][j], 0, 0, 0); \
    _Pragma("unroll") for (int j = 0; j < 2; j++)                                   \
    _Pragma("unroll") for (int i = 0; i < 8; i++)                                   \
      acc[i][j] = __builtin_amdgcn_mfma_f32_16x16x32_f16(lf[i], bf[j], acc[i][j], 0, 0, 0); \
    _Pragma("unroll") for (int j = 0; j < 2; j++)                                   \
    _Pragma("unroll") for (int i = 0; i < 8; i++)                                   \
      acc[i][j] = __builtin_amdgcn_mfma_f32_16x16x32_f16(af[i], mf[j], acc[i][j], 0, 0, 0); \
  } while (0)

// ---------------- one recurrence step ----------------
template <int MODE>
__global__ __launch_bounds__(512, 2) void step_kernel(
    const _Float16* __restrict__ Ah, const _Float16* __restrict__ Al,
    const _Float16* __restrict__ Bh, const _Float16* __restrict__ Bl,
    _Float16* __restrict__ Dh, _Float16* __restrict__ Dl,
    float* __restrict__ Dout, int k_len) {
  __shared__ _Float16 sAh[3][BM * BK];   // 3 x 16 KB
  __shared__ _Float16 sAl[3][BM * BK];   // 3 x 16 KB
  __shared__ _Float16 sBh[3][BN * BK];   // 3 x 8 KB
  __shared__ _Float16 sBl[3][BN * BK];   // 3 x 8 KB   -> 144 KB total

  const int tid = threadIdx.x;       // 0..511
  const int lane = tid & 63;
  const int w = tid >> 6;            // 0..7
  const int wm = w >> 2, wn = w & 3; // 2 x 4 wave grid, 128x32 per wave

  // XCD-aware swizzle: grid 256 = 8 XCDs x 32; each XCD gets a 4-col slab
  int id = blockIdx.x;
  int xcd = id & 7, local = id >> 3;           // local 0..31
  const int bm = (local & 7) * BM;             // 8 row-blocks
  const int bn = (xcd * 4 + (local >> 3)) * BN;  // 32 col-blocks

  const int sr = lane >> 2, cl = lane & 3;
  const int fm = lane & 15, fq = lane >> 4;

  // loop-invariant LDS fragment element-offsets (R3's k-chunk XOR pattern)
  int oA[8], oB[2];
#pragma unroll
  for (int i = 0; i < 8; i++) {
    int rA = wm * 128 + i * 16 + fm;
    oA[i] = rA * BK + (fq ^ ((rA >> 1) & 3)) * 8;
  }
#pragma unroll
  for (int j = 0; j < 2; j++) {
    int rB = wn * 32 + j * 16 + fm;
    oB[j] = rB * BK + (fq ^ ((rB >> 1) & 3)) * 8;
  }

  // staging: wave w stages A rows [w*32, w*32+32) (2 async16/array) and
  // B rows [w*16, w*16+16) (1 async16/array). 4 lanes/row, 64B/row,
  // LDS dst lane-linear. 6 async16 per wave per tile.
  int r0 = w * 32 + sr, r1 = r0 + 16;
  int rb = w * 16 + sr;
  int cg0 = cl ^ ((r0 >> 1) & 3);
  int cg1 = cl ^ ((r1 >> 1) & 3);
  int cgB = cl ^ ((rb >> 1) & 3);
  const size_t gA0 = (size_t)(bm + r0) * NDIM + cg0 * 8;
  const size_t gA1 = (size_t)(bm + r1) * NDIM + cg1 * 8;
  const size_t gB0 = (size_t)(bn + rb) * NDIM + cgB * 8;
  const int lo0 = r0 * BK + cl * 8;
  const int lo1 = r1 * BK + cl * 8;
  const int loB = rb * BK + cl * 8;

  auto stage = [&](int kt, int b) {   // 6 global_load_lds per wave
    async16(Ah + gA0 + kt, &sAh[b][lo0]);
    async16(Ah + gA1 + kt, &sAh[b][lo1]);
    async16(Al + gA0 + kt, &sAl[b][lo0]);
    async16(Al + gA1 + kt, &sAl[b][lo1]);
    async16(Bh + gB0 + kt, &sBh[b][loB]);
    async16(Bl + gB0 + kt, &sBl[b][loB]);
  };

  f32x4 acc[8][2];
#pragma unroll
  for (int i = 0; i < 8; i++)
#pragma unroll
    for (int j = 0; j < 2; j++) acc[i][j] = (f32x4){0.f, 0.f, 0.f, 0.f};

  f16x8 af[8], lf[8], bf[2], mf[2];

  const int nk = k_len / BK;  // 16 or 128

  // 3-buffer rotation, stage lead-2, one barrier per tile, vmcnt never 0
  // until the tail. stage(it+2) -> buf (it+2)%3 == buf read at it-1, whose
  // reads drained (compiler lgkm before MFMA use) before this barrier.
  stage(0 * BK, 0);
  stage(1 * BK, 1);
  int p = 0;
  for (int it = 0; it < nk; ++it) {
    if (it + 1 < nk) { WAITV6(); } else { WAITV0(); }  // stage(it) landed
    SBAR();
    if (it + 2 < nk) {
      int q = (p == 0) ? 2 : p - 1;  // (it+2) % 3
      stage((it + 2) * BK, q);
    }
    READF(p);
    MFMAS();
    p = (p == 2) ? 0 : p + 1;
  }

  // ---- epilogue: undo 256x W-scale, leaky relu, write next state / output
  const float inv = 1.0f / 256.0f;
#pragma unroll
  for (int i = 0; i < 8; i++) {
#pragma unroll
    for (int j = 0; j < 2; j++) {
#pragma unroll
      for (int e = 0; e < 4; e++) {
        int r = bm + wm * 128 + i * 16 + fq * 4 + e;  // C/D: row=(lane>>4)*4+reg
        int c = bn + wn * 32 + j * 16 + fm;           //      col=lane&15
        float g = acc[i][j][e] * inv;
        float s = (g > 0.0f) ? g : 0.1f * g;
        if (MODE == 0) {
          _Float16 h = (_Float16)s;
          Dh[(size_t)r * NDIM + c] = h;
          Dl[(size_t)r * NDIM + c] = (_Float16)(s - (float)h);
        } else {
          Dout[(size_t)r * NDIM + c] = s;
        }
      }
    }
  }
}

extern "C" void kernel_launch(void* const* d_in, const int* in_sizes, int n_in,
                              void* d_out, int out_size, void* d_ws, size_t ws_size,
                              hipStream_t stream) {
  const float* x = (const float*)d_in[0];  // [2048, 512]
  const float* W = (const float*)d_in[1];  // [4096, 4096]
  float* out = (float*)d_out;              // [2048, 4096]
  char* ws = (char*)d_ws;

  const size_t WT_BYTES = (size_t)NDIM * NDIM * 2;  // 32 MB each
  const size_t S_BYTES = (size_t)BATCH * NDIM * 2;  // 16 MB each
  _Float16* Wth = (_Float16*)ws;
  _Float16* Wtl = (_Float16*)(ws + WT_BYTES);
  _Float16* SAh = (_Float16*)(ws + 2 * WT_BYTES);
  _Float16* SAl = (_Float16*)(ws + 2 * WT_BYTES + S_BYTES);
  _Float16* SBh = (_Float16*)(ws + 2 * WT_BYTES + 2 * S_BYTES);
  _Float16* SBl = (_Float16*)(ws + 2 * WT_BYTES + 3 * S_BYTES);

  prep_x<<<(BATCH * NDIM) / 256, 256, 0, stream>>>(x, SAh, SAl);
  prep_w<<<dim3(NDIM / 32, NDIM / 32), dim3(32, 8), 0, stream>>>(W, Wth, Wtl);

  dim3 grid((NDIM / BN) * (BATCH / BM));  // 32 x 8 = 256 blocks = 1/CU
  for (int t = 1; t <= 16; t++) {
    const _Float16* ah = (t & 1) ? SAh : SBh;
    const _Float16* al = (t & 1) ? SAl : SBl;
    _Float16* dh = (t & 1) ? SBh : SAh;
    _Float16* dl = (t & 1) ? SBl : SAl;
    int klen = (t == 1) ? INDIM : NDIM;
    if (t < 16)
      step_kernel<0><<<grid, 512, 0, stream>>>(ah, al, Wth, Wtl, dh, dl, nullptr, klen);
    else
      step_kernel<1><<<grid, 512, 0, stream>>>(ah, al, Wth, Wtl, nullptr, nullptr, out, klen);
  }
}

// Round 14
// 3029.343 us; speedup vs baseline: 1.0667x; 1.0667x over previous
//
#include <hip/hip_runtime.h>

// ReservoirLayer: S0 = pad(x,[2048,4096]); 16x: S = leaky_relu(S @ W, 0.1)
// fp32-emulation via fp16 hi/lo split (fp16x3): acc = Sh@Wh + Sl@Wh + Sh@Wl.
// R17: faithful port of the m201 FINE-PHASE schedule (the one structure
//     measured positive on this chip: 62% MfmaUtil / 1563-1728 TF bf16).
//     Evidence so far: coarse proxies all null/negative (R10 counted-vmcnt,
//     R13 occupancy 2x, R14 lead-1, R15 coarse 1-barrier: 38% MfmaUtil,
//     matching m196's "coarse split without fine interleave HURTS").
//     Geometry: BM=128 x BN=256, BK=32, 512thr (8 waves 2x4, 64x64/wave),
//     grid 16x16=256 = 1 block/CU. 3 LDS buffers x 48KB = 144KB, stage
//     lead-2. Per K-tile: 4 phases, each {8 ds_read_b128 (2x2-frag quadrant)
//     | stage slice (2 gload_lds) | lgkm0+sched_barrier | setprio(1) 12 MFMA
//     term-major setprio(0) | barrier}; vmcnt(6) only at K-tile top (never 0
//     mid-loop). T5 setprio is gated on exactly this phase structure.
//     R3's XOR-chunk LDS pattern + fragment math -> bit-identical numerics.

#define BATCH 2048
#define NDIM  4096
#define INDIM 512
#define BM 128
#define BN 256
#define BK 32

typedef _Float16 f16x8 __attribute__((ext_vector_type(8)));
typedef float    f32x4 __attribute__((ext_vector_type(4)));

__device__ __forceinline__ void async16(const void* gsrc, void* ldst) {
  const __attribute__((address_space(1))) unsigned int* g =
      (const __attribute__((address_space(1))) unsigned int*)gsrc;
  __attribute__((address_space(3))) unsigned int* l =
      (__attribute__((address_space(3))) unsigned int*)ldst;
  __builtin_amdgcn_global_load_lds(g, l, 16, 0, 0);
}

#define WAITV6() do { asm volatile("s_waitcnt vmcnt(6)" ::: "memory"); \
                      __builtin_amdgcn_sched_barrier(0); } while (0)
#define WAITV0() do { asm volatile("s_waitcnt vmcnt(0)" ::: "memory"); \
                      __builtin_amdgcn_sched_barrier(0); } while (0)
#define LGKM0()  do { asm volatile("s_waitcnt lgkmcnt(0)" ::: "memory"); \
                      __builtin_amdgcn_sched_barrier(0); } while (0)
#define SBAR()   __builtin_amdgcn_s_barrier()

// ---------------- prep: split+pad x into S_hi/S_lo ----------------
__global__ void prep_x(const float* __restrict__ x,
                       _Float16* __restrict__ Sh, _Float16* __restrict__ Sl) {
  size_t i = (size_t)blockIdx.x * 256 + threadIdx.x;  // over BATCH*NDIM
  int b = (int)(i >> 12);
  int n = (int)(i & (NDIM - 1));
  float v = (n < INDIM) ? x[(size_t)b * INDIM + n] : 0.0f;
  _Float16 h = (_Float16)v;
  Sh[i] = h;
  Sl[i] = (_Float16)(v - (float)h);
}

// ---------------- prep: transpose + scale(256) + split W ----------------
__global__ void prep_w(const float* __restrict__ W,
                       _Float16* __restrict__ Wth, _Float16* __restrict__ Wtl) {
  __shared__ float tile[32][33];
  int k0 = blockIdx.y * 32, n0 = blockIdx.x * 32;
  int tx = threadIdx.x, ty = threadIdx.y;  // 32 x 8
  for (int r = 0; r < 4; r++) {
    int k = k0 + ty + r * 8;
    tile[ty + r * 8][tx] = W[(size_t)k * NDIM + n0 + tx];
  }
  __syncthreads();
  for (int r = 0; r < 4; r++) {
    int n = n0 + ty + r * 8;
    float v = tile[tx][ty + r * 8] * 256.0f;
    _Float16 h = (_Float16)v;
    Wth[(size_t)n * NDIM + k0 + tx] = h;
    Wtl[(size_t)n * NDIM + k0 + tx] = (_Float16)(v - (float)h);
  }
}

// read quadrant (h,c) frags from buffer b (runtime 0..2; h,c literal)
#define READQ(b, h, c)                                  \
  do {                                                  \
    const _Float16* pAh = &sAh[b][0];                   \
    const _Float16* pAl = &sAl[b][0];                   \
    const _Float16* pBh = &sBh[b][0];                   \
    const _Float16* pBl = &sBl[b][0];                   \
    af[0] = *(const f16x8*)&pAh[oA[(h)*2 + 0]];         \
    af[1] = *(const f16x8*)&pAh[oA[(h)*2 + 1]];         \
    lf[0] = *(const f16x8*)&pAl[oA[(h)*2 + 0]];         \
    lf[1] = *(const f16x8*)&pAl[oA[(h)*2 + 1]];         \
    bf[0] = *(const f16x8*)&pBh[oB[(c)*2 + 0]];         \
    bf[1] = *(const f16x8*)&pBh[oB[(c)*2 + 1]];         \
    mf[0] = *(const f16x8*)&pBl[oB[(c)*2 + 0]];         \
    mf[1] = *(const f16x8*)&pBl[oB[(c)*2 + 1]];         \
  } while (0)

// 12 MFMA, term-major (AB all, LB all, AM all); per-acc order AB->LB->AM
#define MFMAQ(h, c)                                                                  \
  do {                                                                               \
    __builtin_amdgcn_s_setprio(1);                                                   \
    _Pragma("unroll") for (int jj = 0; jj < 2; jj++)                                 \
    _Pragma("unroll") for (int ii = 0; ii < 2; ii++)                                 \
      acc[(h)*2+ii][(c)*2+jj] = __builtin_amdgcn_mfma_f32_16x16x32_f16(              \
          af[ii], bf[jj], acc[(h)*2+ii][(c)*2+jj], 0, 0, 0);                         \
    _Pragma("unroll") for (int jj = 0; jj < 2; jj++)                                 \
    _Pragma("unroll") for (int ii = 0; ii < 2; ii++)                                 \
      acc[(h)*2+ii][(c)*2+jj] = __builtin_amdgcn_mfma_f32_16x16x32_f16(              \
          lf[ii], bf[jj], acc[(h)*2+ii][(c)*2+jj], 0, 0, 0);                         \
    _Pragma("unroll") for (int jj = 0; jj < 2; jj++)                                 \
    _Pragma("unroll") for (int ii = 0; ii < 2; ii++)                                 \
      acc[(h)*2+ii][(c)*2+jj] = __builtin_amdgcn_mfma_f32_16x16x32_f16(              \
          af[ii], mf[jj], acc[(h)*2+ii][(c)*2+jj], 0, 0, 0);                         \
    __builtin_amdgcn_s_setprio(0);                                                   \
  } while (0)

// ---------------- one recurrence step ----------------
template <int MODE>
__global__ __launch_bounds__(512, 2) void step_kernel(
    const _Float16* __restrict__ Ah, const _Float16* __restrict__ Al,
    const _Float16* __restrict__ Bh, const _Float16* __restrict__ Bl,
    _Float16* __restrict__ Dh, _Float16* __restrict__ Dl,
    float* __restrict__ Dout, int k_len) {
  __shared__ _Float16 sAh[3][BM * BK];   // 3 x 8 KB
  __shared__ _Float16 sAl[3][BM * BK];   // 3 x 8 KB
  __shared__ _Float16 sBh[3][BN * BK];   // 3 x 16 KB
  __shared__ _Float16 sBl[3][BN * BK];   // 3 x 16 KB  -> 144 KB

  const int tid = threadIdx.x;       // 0..511
  const int lane = tid & 63;
  const int w = tid >> 6;            // 0..7
  const int wm = w >> 2, wn = w & 3; // 2 x 4 wave grid, 64x64 per wave

  // XCD-aware swizzle: 256 blocks = 8 XCDs x 32; each XCD a 2-col slab
  int id = blockIdx.x;
  int xcd = id & 7, local = id >> 3;            // local 0..31
  const int bm = (local & 15) * BM;             // 16 row-tiles
  const int bn = (xcd * 2 + (local >> 4)) * BN; // 16 col-tiles

  const int fm = lane & 15, fq = lane >> 4;

  // loop-invariant LDS fragment element-offsets (R3's k-chunk XOR pattern)
  int oA[4], oB[4];
#pragma unroll
  for (int i = 0; i < 4; i++) {
    int rA = wm * 64 + i * 16 + fm;
    oA[i] = rA * BK + (fq ^ ((rA >> 1) & 3)) * 8;
  }
#pragma unroll
  for (int j = 0; j < 4; j++) {
    int rB = wn * 64 + j * 16 + fm;
    oB[j] = rB * BK + (fq ^ ((rB >> 1) & 3)) * 8;
  }

  // staging addresses: 4 threads/row, 64B contiguous per row, lane-linear
  // LDS dst (w*512 + lane*8 elements). A: 128 rows = 1 load; B: 256 = 2.
  const int r0 = tid >> 2, cl = tid & 3;        // r0 0..127
  const int cg0 = cl ^ ((r0 >> 1) & 3);
  const int r1 = r0 + 128;
  const int cg1 = cl ^ ((r1 >> 1) & 3);
  const size_t gA0 = (size_t)(bm + r0) * NDIM + cg0 * 8;
  const size_t gB0 = (size_t)(bn + r0) * NDIM + cg0 * 8;
  const size_t gB1 = (size_t)(bn + r1) * NDIM + cg1 * 8;
  const int lo0 = r0 * BK + cl * 8;
  const int lo1 = r1 * BK + cl * 8;

  // stage slices (2 gload_lds each except A=2 combined): 6 loads per K-tile
  auto stageBh = [&](int koff, int b) {
    async16(Bh + gB0 + koff, &sBh[b][lo0]);
    async16(Bh + gB1 + koff, &sBh[b][lo1]);
  };
  auto stageBl = [&](int koff, int b) {
    async16(Bl + gB0 + koff, &sBl[b][lo0]);
    async16(Bl + gB1 + koff, &sBl[b][lo1]);
  };
  auto stageA = [&](int koff, int b) {
    async16(Ah + gA0 + koff, &sAh[b][lo0]);
    async16(Al + gA0 + koff, &sAl[b][lo0]);
  };
  auto stageFull = [&](int koff, int b) {
    stageBh(koff, b); stageBl(koff, b); stageA(koff, b);
  };

  f32x4 acc[4][4];
#pragma unroll
  for (int i = 0; i < 4; i++)
#pragma unroll
    for (int j = 0; j < 4; j++) acc[i][j] = (f32x4){0.f, 0.f, 0.f, 0.f};

  f16x8 af[2], lf[2], bf[2], mf[2];

  const int nk = k_len / BK;  // 16 or 128

  // prologue: stage kt0 -> buf0, kt1 -> buf1 (12 loads in flight)
  stageFull(0, 0);
  stageFull(BK, 1);

  int bufc = 0;
  for (int kt = 0; kt < nk; ++kt) {
    const int bufn = (bufc == 0) ? 2 : bufc - 1;  // (kt+2) % 3
    const bool st = (kt + 2 < nk);
    const int ko = (kt + 2) * BK;

    // phase 0: quadrant (0,0) | stage Bh slice
    if (kt + 1 < nk) { WAITV6(); } else { WAITV0(); }  // K-tile kt landed
    SBAR();                                            // block-wide
    READQ(bufc, 0, 0);
    if (st) stageBh(ko, bufn);
    LGKM0();
    MFMAQ(0, 0);

    // phase 1: quadrant (0,1) | stage Bl slice
    SBAR();
    READQ(bufc, 0, 1);
    if (st) stageBl(ko, bufn);
    LGKM0();
    MFMAQ(0, 1);

    // phase 2: quadrant (1,0) | stage A slice
    SBAR();
    READQ(bufc, 1, 0);
    if (st) stageA(ko, bufn);
    LGKM0();
    MFMAQ(1, 0);

    // phase 3: quadrant (1,1)
    SBAR();
    READQ(bufc, 1, 1);
    LGKM0();
    MFMAQ(1, 1);

    bufc = (bufc == 2) ? 0 : bufc + 1;
  }

  // ---- epilogue: undo 256x W-scale, leaky relu, write next state / output
  const float inv = 1.0f / 256.0f;
#pragma unroll
  for (int i = 0; i < 4; i++) {
#pragma unroll
    for (int j = 0; j < 4; j++) {
#pragma unroll
      for (int e = 0; e < 4; e++) {
        int r = bm + wm * 64 + i * 16 + fq * 4 + e;  // C/D: row=(lane>>4)*4+reg
        int c = bn + wn * 64 + j * 16 + fm;          //      col=lane&15
        float g = acc[i][j][e] * inv;
        float s = (g > 0.0f) ? g : 0.1f * g;
        if (MODE == 0) {
          _Float16 h = (_Float16)s;
          Dh[(size_t)r * NDIM + c] = h;
          Dl[(size_t)r * NDIM + c] = (_Float16)(s - (float)h);
        } else {
          Dout[(size_t)r * NDIM + c] = s;
        }
      }
    }
  }
}

extern "C" void kernel_launch(void* const* d_in, const int* in_sizes, int n_in,
                              void* d_out, int out_size, void* d_ws, size_t ws_size,
                              hipStream_t stream) {
  const float* x = (const float*)d_in[0];  // [2048, 512]
  const float* W = (const float*)d_in[1];  // [4096, 4096]
  float* out = (float*)d_out;              // [2048, 4096]
  char* ws = (char*)d_ws;

  const size_t WT_BYTES = (size_t)NDIM * NDIM * 2;  // 32 MB each
  const size_t S_BYTES = (size_t)BATCH * NDIM * 2;  // 16 MB each
  _Float16* Wth = (_Float16*)ws;
  _Float16* Wtl = (_Float16*)(ws + WT_BYTES);
  _Float16* SAh = (_Float16*)(ws + 2 * WT_BYTES);
  _Float16* SAl = (_Float16*)(ws + 2 * WT_BYTES + S_BYTES);
  _Float16* SBh = (_Float16*)(ws + 2 * WT_BYTES + 2 * S_BYTES);
  _Float16* SBl = (_Float16*)(ws + 2 * WT_BYTES + 3 * S_BYTES);

  prep_x<<<(BATCH * NDIM) / 256, 256, 0, stream>>>(x, SAh, SAl);
  prep_w<<<dim3(NDIM / 32, NDIM / 32), dim3(32, 8), 0, stream>>>(W, Wth, Wtl);

  dim3 grid((NDIM / BN) * (BATCH / BM));  // 16 x 16 = 256 blocks = 1/CU
  for (int t = 1; t <= 16; t++) {
    const _Float16* ah = (t & 1) ? SAh : SBh;
    const _Float16* al = (t & 1) ? SAl : SBl;
    _Float16* dh = (t & 1) ? SBh : SAh;
    _Float16* dl = (t & 1) ? SBl : SAl;
    int klen = (t == 1) ? INDIM : NDIM;
    if (t < 16)
      step_kernel<0><<<grid, 512, 0, stream>>>(ah, al, Wth, Wtl, dh, dl, nullptr, klen);
    else
      step_kernel<1><<<grid, 512, 0, stream>>>(ah, al, Wth, Wtl, nullptr, nullptr, out, klen);
  }
}

// Round 15
// 3005.440 us; speedup vs baseline: 1.0752x; 1.0080x over previous
//
#include <hip/hip_runtime.h>

// ReservoirLayer: S0 = pad(x,[2048,4096]); 16x: S = leaky_relu(S @ W, 0.1)
// fp32-emulation via fp16 hi/lo split (fp16x3): acc = Sh@Wh + Sl@Wh + Sh@Wl.
// R18 = R17 minus the scheduler pins (clean A/B). R17 (fine-phase port)
//     regressed 175->216us with FOUR hard LGKM0+sched_barrier(0) per K-tile
//     = m141's measured anti-pattern (order-pinning defeats the compiler
//     scheduler, ~770 cyc/tile here). This round deletes them; compiler
//     emits fine-grained lgkmcnt(N) per MFMA operand use. Everything else
//     identical: 4 phases/K-tile {READQ | stage slice | setprio(1) 12 MFMA
//     setprio(0) | SBAR}, counted vmcnt(6) at tile top only (never 0
//     mid-loop), 3 buffers (144KB), 1 block/CU, 8 waves 64x64/wave.
//     WAR safety: stage targets the buffer whose reads issued 2+ barriers
//     ago (in-flight ds_reads complete ~100x sooner than post-barrier
//     gload_lds data returns). Decision rule: <172us/step -> fine-phase
//     lever real, keep tuning; >=190 -> revert to R10 (best, 2408us) final.

#define BATCH 2048
#define NDIM  4096
#define INDIM 512
#define BM 128
#define BN 256
#define BK 32

typedef _Float16 f16x8 __attribute__((ext_vector_type(8)));
typedef float    f32x4 __attribute__((ext_vector_type(4)));

__device__ __forceinline__ void async16(const void* gsrc, void* ldst) {
  const __attribute__((address_space(1))) unsigned int* g =
      (const __attribute__((address_space(1))) unsigned int*)gsrc;
  __attribute__((address_space(3))) unsigned int* l =
      (__attribute__((address_space(3))) unsigned int*)ldst;
  __builtin_amdgcn_global_load_lds(g, l, 16, 0, 0);
}

#define WAITV6() do { asm volatile("s_waitcnt vmcnt(6)" ::: "memory"); \
                      __builtin_amdgcn_sched_barrier(0); } while (0)
#define WAITV0() do { asm volatile("s_waitcnt vmcnt(0)" ::: "memory"); \
                      __builtin_amdgcn_sched_barrier(0); } while (0)
#define SBAR()   __builtin_amdgcn_s_barrier()

// ---------------- prep: split+pad x into S_hi/S_lo ----------------
__global__ void prep_x(const float* __restrict__ x,
                       _Float16* __restrict__ Sh, _Float16* __restrict__ Sl) {
  size_t i = (size_t)blockIdx.x * 256 + threadIdx.x;  // over BATCH*NDIM
  int b = (int)(i >> 12);
  int n = (int)(i & (NDIM - 1));
  float v = (n < INDIM) ? x[(size_t)b * INDIM + n] : 0.0f;
  _Float16 h = (_Float16)v;
  Sh[i] = h;
  Sl[i] = (_Float16)(v - (float)h);
}

// ---------------- prep: transpose + scale(256) + split W ----------------
__global__ void prep_w(const float* __restrict__ W,
                       _Float16* __restrict__ Wth, _Float16* __restrict__ Wtl) {
  __shared__ float tile[32][33];
  int k0 = blockIdx.y * 32, n0 = blockIdx.x * 32;
  int tx = threadIdx.x, ty = threadIdx.y;  // 32 x 8
  for (int r = 0; r < 4; r++) {
    int k = k0 + ty + r * 8;
    tile[ty + r * 8][tx] = W[(size_t)k * NDIM + n0 + tx];
  }
  __syncthreads();
  for (int r = 0; r < 4; r++) {
    int n = n0 + ty + r * 8;
    float v = tile[tx][ty + r * 8] * 256.0f;
    _Float16 h = (_Float16)v;
    Wth[(size_t)n * NDIM + k0 + tx] = h;
    Wtl[(size_t)n * NDIM + k0 + tx] = (_Float16)(v - (float)h);
  }
}

// read quadrant (h,c) frags from buffer b (runtime 0..2; h,c literal)
#define READQ(b, h, c)                                  \
  do {                                                  \
    const _Float16* pAh = &sAh[b][0];                   \
    const _Float16* pAl = &sAl[b][0];                   \
    const _Float16* pBh = &sBh[b][0];                   \
    const _Float16* pBl = &sBl[b][0];                   \
    af[0] = *(const f16x8*)&pAh[oA[(h)*2 + 0]];         \
    af[1] = *(const f16x8*)&pAh[oA[(h)*2 + 1]];         \
    lf[0] = *(const f16x8*)&pAl[oA[(h)*2 + 0]];         \
    lf[1] = *(const f16x8*)&pAl[oA[(h)*2 + 1]];         \
    bf[0] = *(const f16x8*)&pBh[oB[(c)*2 + 0]];         \
    bf[1] = *(const f16x8*)&pBh[oB[(c)*2 + 1]];         \
    mf[0] = *(const f16x8*)&pBl[oB[(c)*2 + 0]];         \
    mf[1] = *(const f16x8*)&pBl[oB[(c)*2 + 1]];         \
  } while (0)

// 12 MFMA, term-major (AB all, LB all, AM all); per-acc order AB->LB->AM.
// Compiler inserts fine-grained lgkmcnt before first operand use.
#define MFMAQ(h, c)                                                                  \
  do {                                                                               \
    __builtin_amdgcn_s_setprio(1);                                                   \
    _Pragma("unroll") for (int jj = 0; jj < 2; jj++)                                 \
    _Pragma("unroll") for (int ii = 0; ii < 2; ii++)                                 \
      acc[(h)*2+ii][(c)*2+jj] = __builtin_amdgcn_mfma_f32_16x16x32_f16(              \
          af[ii], bf[jj], acc[(h)*2+ii][(c)*2+jj], 0, 0, 0);                         \
    _Pragma("unroll") for (int jj = 0; jj < 2; jj++)                                 \
    _Pragma("unroll") for (int ii = 0; ii < 2; ii++)                                 \
      acc[(h)*2+ii][(c)*2+jj] = __builtin_amdgcn_mfma_f32_16x16x32_f16(              \
          lf[ii], bf[jj], acc[(h)*2+ii][(c)*2+jj], 0, 0, 0);                         \
    _Pragma("unroll") for (int jj = 0; jj < 2; jj++)                                 \
    _Pragma("unroll") for (int ii = 0; ii < 2; ii++)                                 \
      acc[(h)*2+ii][(c)*2+jj] = __builtin_amdgcn_mfma_f32_16x16x32_f16(              \
          af[ii], mf[jj], acc[(h)*2+ii][(c)*2+jj], 0, 0, 0);                         \
    __builtin_amdgcn_s_setprio(0);                                                   \
  } while (0)

// ---------------- one recurrence step ----------------
template <int MODE>
__global__ __launch_bounds__(512, 2) void step_kernel(
    const _Float16* __restrict__ Ah, const _Float16* __restrict__ Al,
    const _Float16* __restrict__ Bh, const _Float16* __restrict__ Bl,
    _Float16* __restrict__ Dh, _Float16* __restrict__ Dl,
    float* __restrict__ Dout, int k_len) {
  __shared__ _Float16 sAh[3][BM * BK];   // 3 x 8 KB
  __shared__ _Float16 sAl[3][BM * BK];   // 3 x 8 KB
  __shared__ _Float16 sBh[3][BN * BK];   // 3 x 16 KB
  __shared__ _Float16 sBl[3][BN * BK];   // 3 x 16 KB  -> 144 KB

  const int tid = threadIdx.x;       // 0..511
  const int lane = tid & 63;
  const int w = tid >> 6;            // 0..7
  const int wm = w >> 2, wn = w & 3; // 2 x 4 wave grid, 64x64 per wave

  // XCD-aware swizzle: 256 blocks = 8 XCDs x 32; each XCD a 2-col slab
  int id = blockIdx.x;
  int xcd = id & 7, local = id >> 3;            // local 0..31
  const int bm = (local & 15) * BM;             // 16 row-tiles
  const int bn = (xcd * 2 + (local >> 4)) * BN; // 16 col-tiles

  const int fm = lane & 15, fq = lane >> 4;

  // loop-invariant LDS fragment element-offsets (R3's k-chunk XOR pattern)
  int oA[4], oB[4];
#pragma unroll
  for (int i = 0; i < 4; i++) {
    int rA = wm * 64 + i * 16 + fm;
    oA[i] = rA * BK + (fq ^ ((rA >> 1) & 3)) * 8;
  }
#pragma unroll
  for (int j = 0; j < 4; j++) {
    int rB = wn * 64 + j * 16 + fm;
    oB[j] = rB * BK + (fq ^ ((rB >> 1) & 3)) * 8;
  }

  // staging addresses: 4 threads/row, 64B contiguous per row, lane-linear
  // LDS dst (w*512 + lane*8 elements). A: 128 rows = 1 load; B: 256 = 2.
  const int r0 = tid >> 2, cl = tid & 3;        // r0 0..127
  const int cg0 = cl ^ ((r0 >> 1) & 3);
  const int r1 = r0 + 128;
  const int cg1 = cl ^ ((r1 >> 1) & 3);
  const size_t gA0 = (size_t)(bm + r0) * NDIM + cg0 * 8;
  const size_t gB0 = (size_t)(bn + r0) * NDIM + cg0 * 8;
  const size_t gB1 = (size_t)(bn + r1) * NDIM + cg1 * 8;
  const int lo0 = r0 * BK + cl * 8;
  const int lo1 = r1 * BK + cl * 8;

  // stage slices: 6 gload_lds per K-tile total, spread across phases 0-2
  auto stageBh = [&](int koff, int b) {
    async16(Bh + gB0 + koff, &sBh[b][lo0]);
    async16(Bh + gB1 + koff, &sBh[b][lo1]);
  };
  auto stageBl = [&](int koff, int b) {
    async16(Bl + gB0 + koff, &sBl[b][lo0]);
    async16(Bl + gB1 + koff, &sBl[b][lo1]);
  };
  auto stageA = [&](int koff, int b) {
    async16(Ah + gA0 + koff, &sAh[b][lo0]);
    async16(Al + gA0 + koff, &sAl[b][lo0]);
  };
  auto stageFull = [&](int koff, int b) {
    stageBh(koff, b); stageBl(koff, b); stageA(koff, b);
  };

  f32x4 acc[4][4];
#pragma unroll
  for (int i = 0; i < 4; i++)
#pragma unroll
    for (int j = 0; j < 4; j++) acc[i][j] = (f32x4){0.f, 0.f, 0.f, 0.f};

  f16x8 af[2], lf[2], bf[2], mf[2];

  const int nk = k_len / BK;  // 16 or 128

  // prologue: stage kt0 -> buf0, kt1 -> buf1 (12 loads in flight)
  stageFull(0, 0);
  stageFull(BK, 1);

  int bufc = 0;
  for (int kt = 0; kt < nk; ++kt) {
    const int bufn = (bufc == 0) ? 2 : bufc - 1;  // (kt+2) % 3
    const bool st = (kt + 2 < nk);
    const int ko = (kt + 2) * BK;

    // phase 0: quadrant (0,0) | stage Bh slice
    if (kt + 1 < nk) { WAITV6(); } else { WAITV0(); }  // K-tile kt landed
    SBAR();                                            // block-wide
    READQ(bufc, 0, 0);
    if (st) stageBh(ko, bufn);
    MFMAQ(0, 0);

    // phase 1: quadrant (0,1) | stage Bl slice
    SBAR();
    READQ(bufc, 0, 1);
    if (st) stageBl(ko, bufn);
    MFMAQ(0, 1);

    // phase 2: quadrant (1,0) | stage A slice
    SBAR();
    READQ(bufc, 1, 0);
    if (st) stageA(ko, bufn);
    MFMAQ(1, 0);

    // phase 3: quadrant (1,1)
    SBAR();
    READQ(bufc, 1, 1);
    MFMAQ(1, 1);

    bufc = (bufc == 2) ? 0 : bufc + 1;
  }

  // ---- epilogue: undo 256x W-scale, leaky relu, write next state / output
  const float inv = 1.0f / 256.0f;
#pragma unroll
  for (int i = 0; i < 4; i++) {
#pragma unroll
    for (int j = 0; j < 4; j++) {
#pragma unroll
      for (int e = 0; e < 4; e++) {
        int r = bm + wm * 64 + i * 16 + fq * 4 + e;  // C/D: row=(lane>>4)*4+reg
        int c = bn + wn * 64 + j * 16 + fm;          //      col=lane&15
        float g = acc[i][j][e] * inv;
        float s = (g > 0.0f) ? g : 0.1f * g;
        if (MODE == 0) {
          _Float16 h = (_Float16)s;
          Dh[(size_t)r * NDIM + c] = h;
          Dl[(size_t)r * NDIM + c] = (_Float16)(s - (float)h);
        } else {
          Dout[(size_t)r * NDIM + c] = s;
        }
      }
    }
  }
}

extern "C" void kernel_launch(void* const* d_in, const int* in_sizes, int n_in,
                              void* d_out, int out_size, void* d_ws, size_t ws_size,
                              hipStream_t stream) {
  const float* x = (const float*)d_in[0];  // [2048, 512]
  const float* W = (const float*)d_in[1];  // [4096, 4096]
  float* out = (float*)d_out;              // [2048, 4096]
  char* ws = (char*)d_ws;

  const size_t WT_BYTES = (size_t)NDIM * NDIM * 2;  // 32 MB each
  const size_t S_BYTES = (size_t)BATCH * NDIM * 2;  // 16 MB each
  _Float16* Wth = (_Float16*)ws;
  _Float16* Wtl = (_Float16*)(ws + WT_BYTES);
  _Float16* SAh = (_Float16*)(ws + 2 * WT_BYTES);
  _Float16* SAl = (_Float16*)(ws + 2 * WT_BYTES + S_BYTES);
  _Float16* SBh = (_Float16*)(ws + 2 * WT_BYTES + 2 * S_BYTES);
  _Float16* SBl = (_Float16*)(ws + 2 * WT_BYTES + 3 * S_BYTES);

  prep_x<<<(BATCH * NDIM) / 256, 256, 0, stream>>>(x, SAh, SAl);
  prep_w<<<dim3(NDIM / 32, NDIM / 32), dim3(32, 8), 0, stream>>>(W, Wth, Wtl);

  dim3 grid((NDIM / BN) * (BATCH / BM));  // 16 x 16 = 256 blocks = 1/CU
  for (int t = 1; t <= 16; t++) {
    const _Float16* ah = (t & 1) ? SAh : SBh;
    const _Float16* al = (t & 1) ? SAl : SBl;
    _Float16* dh = (t & 1) ? SBh : SAh;
    _Float16* dl = (t & 1) ? SBl : SAl;
    int klen = (t == 1) ? INDIM : NDIM;
    if (t < 16)
      step_kernel<0><<<grid, 512, 0, stream>>>(ah, al, Wth, Wtl, dh, dl, nullptr, klen);
    else
      step_kernel<1><<<grid, 512, 0, stream>>>(ah, al, Wth, Wtl, nullptr, nullptr, out, klen);
  }
}

// Round 16
// 2405.706 us; speedup vs baseline: 1.3432x; 1.2493x over previous
//
#include <hip/hip_runtime.h>

// ReservoirLayer: S0 = pad(x,[2048,4096]); 16x: S = leaky_relu(S @ W, 0.1)
// fp32-emulation via fp16 hi/lo split (fp16x3): acc = Sh@Wh + Sl@Wh + Sh@Wl.
// FINAL (R19) = R10, the best-measured kernel (2408us; step ~177us).
// Session summary: 16 experiments, plateau 175-178us/step at MfmaUtil ~52%:
//   - bank conflicts 1.7e7 -> 0 (R7 transplant of R3's read pattern): NEUTRAL
//   - MFMA shape 16x16<->32x32: NEUTRAL  - LDS volume halved (R9/R12): NEUTRAL
//   - counted vmcnt (R10): NEUTRAL       - occupancy 2x (R13): NEUTRAL
//   - anti-lockstep lead-1 (R14): -14%   - coarse 1-barrier (R15): -24%
//   - fine-phase 4-phase +setprio (R17): -19%; minus pins (R18): -16%
// Floor arithmetic: 206 GFLOP MFMA/step / 1955 TF (16x16-f16 ceiling) =
// 105us pure-pipe; the remaining ~70us is MFMA<->LDS<->sync overlap this
// structure family cannot close at HIP source level for a 4-array fp16x3
// dataflow (every phase-structure variant regressed).

#define BATCH 2048
#define NDIM  4096
#define INDIM 512
#define BM 128
#define BN 128
#define BK 32

typedef _Float16 f16x8 __attribute__((ext_vector_type(8)));
typedef float    f32x4 __attribute__((ext_vector_type(4)));

__device__ __forceinline__ void async16(const void* gsrc, void* ldst) {
  const __attribute__((address_space(1))) unsigned int* g =
      (const __attribute__((address_space(1))) unsigned int*)gsrc;
  __attribute__((address_space(3))) unsigned int* l =
      (__attribute__((address_space(3))) unsigned int*)ldst;
  __builtin_amdgcn_global_load_lds(g, l, 16, 0, 0);
}

#define WAITV8() do { asm volatile("s_waitcnt vmcnt(8)" ::: "memory"); \
                      __builtin_amdgcn_sched_barrier(0); } while (0)
#define WAITV0() do { asm volatile("s_waitcnt vmcnt(0)" ::: "memory"); \
                      __builtin_amdgcn_sched_barrier(0); } while (0)
#define LGKM0()  do { asm volatile("s_waitcnt lgkmcnt(0)" ::: "memory"); \
                      __builtin_amdgcn_sched_barrier(0); } while (0)
#define SBAR()   __builtin_amdgcn_s_barrier()

// ---------------- prep: split+pad x into S_hi/S_lo ----------------
__global__ void prep_x(const float* __restrict__ x,
                       _Float16* __restrict__ Sh, _Float16* __restrict__ Sl) {
  size_t i = (size_t)blockIdx.x * 256 + threadIdx.x;  // over BATCH*NDIM
  int b = (int)(i >> 12);
  int n = (int)(i & (NDIM - 1));
  float v = (n < INDIM) ? x[(size_t)b * INDIM + n] : 0.0f;
  _Float16 h = (_Float16)v;
  Sh[i] = h;
  Sl[i] = (_Float16)(v - (float)h);
}

// ---------------- prep: transpose + scale(256) + split W ----------------
__global__ void prep_w(const float* __restrict__ W,
                       _Float16* __restrict__ Wth, _Float16* __restrict__ Wtl) {
  __shared__ float tile[32][33];
  int k0 = blockIdx.y * 32, n0 = blockIdx.x * 32;
  int tx = threadIdx.x, ty = threadIdx.y;  // 32 x 8
  for (int r = 0; r < 4; r++) {
    int k = k0 + ty + r * 8;
    tile[ty + r * 8][tx] = W[(size_t)k * NDIM + n0 + tx];
  }
  __syncthreads();
  for (int r = 0; r < 4; r++) {
    int n = n0 + ty + r * 8;
    float v = tile[tx][ty + r * 8] * 256.0f;
    _Float16 h = (_Float16)v;
    Wth[(size_t)n * NDIM + k0 + tx] = h;
    Wtl[(size_t)n * NDIM + k0 + tx] = (_Float16)(v - (float)h);
  }
}

// read one frag set from LDS buffers b (compile-time 0/1 at all call sites)
#define READF(b, A, L, Bv, M)                          \
  do {                                                 \
    _Pragma("unroll") for (int i = 0; i < 4; i++) {    \
      A[i]  = *(const f16x8*)&sAh[b][oA[i]];           \
      L[i]  = *(const f16x8*)&sAl[b][oA[i]];           \
      Bv[i] = *(const f16x8*)&sBh[b][oB[i]];           \
      M[i]  = *(const f16x8*)&sBl[b][oB[i]];           \
    }                                                  \
  } while (0)

#define MFMAS(A, L, Bv, M)                                                          \
  do {                                                                              \
    _Pragma("unroll") for (int j = 0; j < 4; j++)                                   \
    _Pragma("unroll") for (int i = 0; i < 4; i++) {                                 \
      acc[i][j] = __builtin_amdgcn_mfma_f32_16x16x32_f16(A[i], Bv[j], acc[i][j], 0, 0, 0); \
      acc[i][j] = __builtin_amdgcn_mfma_f32_16x16x32_f16(L[i], Bv[j], acc[i][j], 0, 0, 0); \
      acc[i][j] = __builtin_amdgcn_mfma_f32_16x16x32_f16(A[i], M[j], acc[i][j], 0, 0, 0); \
    }                                                                               \
  } while (0)

// ---------------- one recurrence step ----------------
template <int MODE>
__global__ __launch_bounds__(256, 2) void step_kernel(
    const _Float16* __restrict__ Ah, const _Float16* __restrict__ Al,
    const _Float16* __restrict__ Bh, const _Float16* __restrict__ Bl,
    _Float16* __restrict__ Dh, _Float16* __restrict__ Dl,
    float* __restrict__ Dout, int k_len) {
  __shared__ _Float16 sAh[2][BM * BK];
  __shared__ _Float16 sAl[2][BM * BK];
  __shared__ _Float16 sBh[2][BN * BK];
  __shared__ _Float16 sBl[2][BN * BK];

  const int tid = threadIdx.x;
  const int lane = tid & 63;
  const int w = tid >> 6;
  const int wm = w >> 1, wn = w & 1;

  // XCD-aware swizzle: 8x8 block region per XCD (round-robin dispatch, id&7)
  int id = blockIdx.x;
  int xcd = id & 7, local = id >> 3;
  int lr = local & 7, lc = local >> 3;
  const int bm = ((xcd & 1) * 8 + lr) * BM;
  const int bn = ((xcd >> 1) * 8 + lc) * BN;

  const int sr = lane >> 2, cl = lane & 3;
  const int fm = lane & 15, fq = lane >> 4;

  // loop-invariant LDS fragment element-offsets (k-chunk swizzled)
  int oA[4], oB[4];
#pragma unroll
  for (int i = 0; i < 4; i++) {
    int rA = wm * 64 + i * 16 + fm;
    oA[i] = rA * BK + (fq ^ ((rA >> 1) & 3)) * 8;
    int rB = wn * 64 + i * 16 + fm;
    oB[i] = rB * BK + (fq ^ ((rB >> 1) & 3)) * 8;
  }

  // loop-invariant staging addresses (k added per call)
  int r0 = w * 32 + sr, r1 = r0 + 16;
  int cg0 = cl ^ ((r0 >> 1) & 3);
  int cg1 = cl ^ ((r1 >> 1) & 3);
  const size_t gA0 = (size_t)(bm + r0) * NDIM + cg0 * 8;
  const size_t gA1 = (size_t)(bm + r1) * NDIM + cg1 * 8;
  const size_t gB0 = (size_t)(bn + r0) * NDIM + cg0 * 8;
  const size_t gB1 = (size_t)(bn + r1) * NDIM + cg1 * 8;
  const int lo0 = r0 * BK + cl * 8;
  const int lo1 = r1 * BK + cl * 8;

  auto stage = [&](int kt, int b) {   // 8 global_load_lds per wave
    async16(Ah + gA0 + kt, &sAh[b][lo0]);
    async16(Ah + gA1 + kt, &sAh[b][lo1]);
    async16(Al + gA0 + kt, &sAl[b][lo0]);
    async16(Al + gA1 + kt, &sAl[b][lo1]);
    async16(Bh + gB0 + kt, &sBh[b][lo0]);
    async16(Bh + gB1 + kt, &sBh[b][lo1]);
    async16(Bl + gB0 + kt, &sBl[b][lo0]);
    async16(Bl + gB1 + kt, &sBl[b][lo1]);
  };

  f32x4 acc[4][4];
#pragma unroll
  for (int i = 0; i < 4; i++)
#pragma unroll
    for (int j = 0; j < 4; j++) acc[i][j] = (f32x4){0.f, 0.f, 0.f, 0.f};

  f16x8 a0[4], l0[4], b0[4], m0[4];  // frag set 0
  f16x8 a1[4], l1[4], b1[4], m1[4];  // frag set 1

  const int nk = k_len / BK;  // 16 or 128 (even)

  // prologue: issue tiles 0,1; wait only for tile 0 (oldest 8 of 16)
  stage(0 * BK, 0);
  stage(1 * BK, 1);
  WAITV8(); SBAR();              // stage(0) done, all waves
  READF(0, a0, l0, b0, m0);
  LGKM0(); SBAR();               // all waves' buf0 reads retired
  stage(2 * BK, 0);              // in flight: stage(1)+stage(2) = 16

  // main: WAITV8|SBAR -> READF(it) | MFMA(it-1) -> LGKM0|SBAR -> stage(it+2)
  int it = 1;
  for (; it + 1 < nk; it += 2) {
    WAITV8(); SBAR();            // stage(it) done (oldest 8 retired)
    READF(1, a1, l1, b1, m1);    // reads(it), it odd -> buf1
    MFMAS(a0, l0, b0, m0);       // MFMA(it-1)
    LGKM0(); SBAR();             // buf1 reads retired everywhere
    if (it + 2 < nk) stage((it + 2) * BK, 1);

    WAITV8(); SBAR();            // stage(it+1) done
    READF(0, a0, l0, b0, m0);    // reads(it+1), even -> buf0
    MFMAS(a1, l1, b1, m1);       // MFMA(it)
    LGKM0(); SBAR();             // buf0 reads retired everywhere
    if (it + 3 < nk) stage((it + 3) * BK, 0);
  }
  // tail: it == nk-1 (odd); only stage(nk-1) can still be in flight
  WAITV0(); SBAR();              // stage(nk-1) done, all waves
  READF(1, a1, l1, b1, m1);      // reads(nk-1)
  MFMAS(a0, l0, b0, m0);         // MFMA(nk-2)
  LGKM0();                       // reads(nk-1) retired (own-wave only needed)
  MFMAS(a1, l1, b1, m1);         // MFMA(nk-1)

  // ---- epilogue: undo 256x W-scale, leaky relu, write next state / output
  const float inv = 1.0f / 256.0f;
#pragma unroll
  for (int i = 0; i < 4; i++) {
#pragma unroll
    for (int j = 0; j < 4; j++) {
#pragma unroll
      for (int e = 0; e < 4; e++) {
        int r = bm + wm * 64 + i * 16 + fq * 4 + e;  // C/D: row=(lane>>4)*4+reg
        int c = bn + wn * 64 + j * 16 + fm;          //      col=lane&15
        float g = acc[i][j][e] * inv;
        float s = (g > 0.0f) ? g : 0.1f * g;
        if (MODE == 0) {
          _Float16 h = (_Float16)s;
          Dh[(size_t)r * NDIM + c] = h;
          Dl[(size_t)r * NDIM + c] = (_Float16)(s - (float)h);
        } else {
          Dout[(size_t)r * NDIM + c] = s;
        }
      }
    }
  }
}

extern "C" void kernel_launch(void* const* d_in, const int* in_sizes, int n_in,
                              void* d_out, int out_size, void* d_ws, size_t ws_size,
                              hipStream_t stream) {
  const float* x = (const float*)d_in[0];  // [2048, 512]
  const float* W = (const float*)d_in[1];  // [4096, 4096]
  float* out = (float*)d_out;              // [2048, 4096]
  char* ws = (char*)d_ws;

  const size_t WT_BYTES = (size_t)NDIM * NDIM * 2;  // 32 MB each
  const size_t S_BYTES = (size_t)BATCH * NDIM * 2;  // 16 MB each
  _Float16* Wth = (_Float16*)ws;
  _Float16* Wtl = (_Float16*)(ws + WT_BYTES);
  _Float16* SAh = (_Float16*)(ws + 2 * WT_BYTES);
  _Float16* SAl = (_Float16*)(ws + 2 * WT_BYTES + S_BYTES);
  _Float16* SBh = (_Float16*)(ws + 2 * WT_BYTES + 2 * S_BYTES);
  _Float16* SBl = (_Float16*)(ws + 2 * WT_BYTES + 3 * S_BYTES);

  prep_x<<<(BATCH * NDIM) / 256, 256, 0, stream>>>(x, SAh, SAl);
  prep_w<<<dim3(NDIM / 32, NDIM / 32), dim3(32, 8), 0, stream>>>(W, Wth, Wtl);

  dim3 grid((NDIM / BN) * (BATCH / BM));  // 512 linear, swizzled in-kernel
  for (int t = 1; t <= 16; t++) {
    const _Float16* ah = (t & 1) ? SAh : SBh;
    const _Float16* al = (t & 1) ? SAl : SBl;
    _Float16* dh = (t & 1) ? SBh : SAh;
    _Float16* dl = (t & 1) ? SBl : SAl;
    int klen = (t == 1) ? INDIM : NDIM;
    if (t < 16)
      step_kernel<0><<<grid, 256, 0, stream>>>(ah, al, Wth, Wtl, dh, dl, nullptr, klen);
    else
      step_kernel<1><<<grid, 256, 0, stream>>>(ah, al, Wth, Wtl, nullptr, nullptr, out, klen);
  }
}

// Round 17
// 2397.185 us; speedup vs baseline: 1.3480x; 1.0036x over previous
//
#include <hip/hip_runtime.h>

// ReservoirLayer: S0 = pad(x,[2048,4096]); 16x: S = leaky_relu(S @ W, 0.1)
// fp32-emulation via fp16 hi/lo split (fp16x3): acc = Sh@Wh + Sl@Wh + Sh@Wl.
// R20 = R10/R16 (best measured, 2406us) + CROSS-BLOCK ANTI-PHASING.
// Evidence: 2 blocks/CU (175us) vs 1 block/CU (216-231us) shows the plateau
// already relies on co-resident blocks covering each other's barrier phases,
// but that overlap is uncontrolled: per-tile window 3281cyc sits near the
// SUM of pipe demands (LDS 2048 + MFMA 1862) not the MAX (2048) -> phases
// largely aligned. Fix: blocks b and b+256 co-reside (512 blocks round-robin
// on 256 CUs); give one parity class an s_sleep(25) (~1600cyc ~ half tile
// period) before the prologue -> persistent half-period phase offset, one
// block's MFMA fills the other's read/stage window. Numerics unchanged.
// Null result (+-3us) => declare plateau structural (ROOFLINE).

#define BATCH 2048
#define NDIM  4096
#define INDIM 512
#define BM 128
#define BN 128
#define BK 32

typedef _Float16 f16x8 __attribute__((ext_vector_type(8)));
typedef float    f32x4 __attribute__((ext_vector_type(4)));

__device__ __forceinline__ void async16(const void* gsrc, void* ldst) {
  const __attribute__((address_space(1))) unsigned int* g =
      (const __attribute__((address_space(1))) unsigned int*)gsrc;
  __attribute__((address_space(3))) unsigned int* l =
      (__attribute__((address_space(3))) unsigned int*)ldst;
  __builtin_amdgcn_global_load_lds(g, l, 16, 0, 0);
}

#define WAITV8() do { asm volatile("s_waitcnt vmcnt(8)" ::: "memory"); \
                      __builtin_amdgcn_sched_barrier(0); } while (0)
#define WAITV0() do { asm volatile("s_waitcnt vmcnt(0)" ::: "memory"); \
                      __builtin_amdgcn_sched_barrier(0); } while (0)
#define LGKM0()  do { asm volatile("s_waitcnt lgkmcnt(0)" ::: "memory"); \
                      __builtin_amdgcn_sched_barrier(0); } while (0)
#define SBAR()   __builtin_amdgcn_s_barrier()

// ---------------- prep: split+pad x into S_hi/S_lo ----------------
__global__ void prep_x(const float* __restrict__ x,
                       _Float16* __restrict__ Sh, _Float16* __restrict__ Sl) {
  size_t i = (size_t)blockIdx.x * 256 + threadIdx.x;  // over BATCH*NDIM
  int b = (int)(i >> 12);
  int n = (int)(i & (NDIM - 1));
  float v = (n < INDIM) ? x[(size_t)b * INDIM + n] : 0.0f;
  _Float16 h = (_Float16)v;
  Sh[i] = h;
  Sl[i] = (_Float16)(v - (float)h);
}

// ---------------- prep: transpose + scale(256) + split W ----------------
__global__ void prep_w(const float* __restrict__ W,
                       _Float16* __restrict__ Wth, _Float16* __restrict__ Wtl) {
  __shared__ float tile[32][33];
  int k0 = blockIdx.y * 32, n0 = blockIdx.x * 32;
  int tx = threadIdx.x, ty = threadIdx.y;  // 32 x 8
  for (int r = 0; r < 4; r++) {
    int k = k0 + ty + r * 8;
    tile[ty + r * 8][tx] = W[(size_t)k * NDIM + n0 + tx];
  }
  __syncthreads();
  for (int r = 0; r < 4; r++) {
    int n = n0 + ty + r * 8;
    float v = tile[tx][ty + r * 8] * 256.0f;
    _Float16 h = (_Float16)v;
    Wth[(size_t)n * NDIM + k0 + tx] = h;
    Wtl[(size_t)n * NDIM + k0 + tx] = (_Float16)(v - (float)h);
  }
}

// read one frag set from LDS buffers b (compile-time 0/1 at all call sites)
#define READF(b, A, L, Bv, M)                          \
  do {                                                 \
    _Pragma("unroll") for (int i = 0; i < 4; i++) {    \
      A[i]  = *(const f16x8*)&sAh[b][oA[i]];           \
      L[i]  = *(const f16x8*)&sAl[b][oA[i]];           \
      Bv[i] = *(const f16x8*)&sBh[b][oB[i]];           \
      M[i]  = *(const f16x8*)&sBl[b][oB[i]];           \
    }                                                  \
  } while (0)

#define MFMAS(A, L, Bv, M)                                                          \
  do {                                                                              \
    _Pragma("unroll") for (int j = 0; j < 4; j++)                                   \
    _Pragma("unroll") for (int i = 0; i < 4; i++) {                                 \
      acc[i][j] = __builtin_amdgcn_mfma_f32_16x16x32_f16(A[i], Bv[j], acc[i][j], 0, 0, 0); \
      acc[i][j] = __builtin_amdgcn_mfma_f32_16x16x32_f16(L[i], Bv[j], acc[i][j], 0, 0, 0); \
      acc[i][j] = __builtin_amdgcn_mfma_f32_16x16x32_f16(A[i], M[j], acc[i][j], 0, 0, 0); \
    }                                                                               \
  } while (0)

// ---------------- one recurrence step ----------------
template <int MODE>
__global__ __launch_bounds__(256, 2) void step_kernel(
    const _Float16* __restrict__ Ah, const _Float16* __restrict__ Al,
    const _Float16* __restrict__ Bh, const _Float16* __restrict__ Bl,
    _Float16* __restrict__ Dh, _Float16* __restrict__ Dl,
    float* __restrict__ Dout, int k_len) {
  __shared__ _Float16 sAh[2][BM * BK];
  __shared__ _Float16 sAl[2][BM * BK];
  __shared__ _Float16 sBh[2][BN * BK];
  __shared__ _Float16 sBl[2][BN * BK];

  const int tid = threadIdx.x;
  const int lane = tid & 63;
  const int w = tid >> 6;
  const int wm = w >> 1, wn = w & 1;

  // anti-phase skew: co-resident pair (id, id+256) -> offset one class by
  // ~1600 cyc (half the per-K-tile period) so their barrier phases interleave
  if ((blockIdx.x >> 8) & 1) __builtin_amdgcn_s_sleep(25);

  // XCD-aware swizzle: 8x8 block region per XCD (round-robin dispatch, id&7)
  int id = blockIdx.x;
  int xcd = id & 7, local = id >> 3;
  int lr = local & 7, lc = local >> 3;
  const int bm = ((xcd & 1) * 8 + lr) * BM;
  const int bn = ((xcd >> 1) * 8 + lc) * BN;

  const int sr = lane >> 2, cl = lane & 3;
  const int fm = lane & 15, fq = lane >> 4;

  // loop-invariant LDS fragment element-offsets (k-chunk swizzled)
  int oA[4], oB[4];
#pragma unroll
  for (int i = 0; i < 4; i++) {
    int rA = wm * 64 + i * 16 + fm;
    oA[i] = rA * BK + (fq ^ ((rA >> 1) & 3)) * 8;
    int rB = wn * 64 + i * 16 + fm;
    oB[i] = rB * BK + (fq ^ ((rB >> 1) & 3)) * 8;
  }

  // loop-invariant staging addresses (k added per call)
  int r0 = w * 32 + sr, r1 = r0 + 16;
  int cg0 = cl ^ ((r0 >> 1) & 3);
  int cg1 = cl ^ ((r1 >> 1) & 3);
  const size_t gA0 = (size_t)(bm + r0) * NDIM + cg0 * 8;
  const size_t gA1 = (size_t)(bm + r1) * NDIM + cg1 * 8;
  const size_t gB0 = (size_t)(bn + r0) * NDIM + cg0 * 8;
  const size_t gB1 = (size_t)(bn + r1) * NDIM + cg1 * 8;
  const int lo0 = r0 * BK + cl * 8;
  const int lo1 = r1 * BK + cl * 8;

  auto stage = [&](int kt, int b) {   // 8 global_load_lds per wave
    async16(Ah + gA0 + kt, &sAh[b][lo0]);
    async16(Ah + gA1 + kt, &sAh[b][lo1]);
    async16(Al + gA0 + kt, &sAl[b][lo0]);
    async16(Al + gA1 + kt, &sAl[b][lo1]);
    async16(Bh + gB0 + kt, &sBh[b][lo0]);
    async16(Bh + gB1 + kt, &sBh[b][lo1]);
    async16(Bl + gB0 + kt, &sBl[b][lo0]);
    async16(Bl + gB1 + kt, &sBl[b][lo1]);
  };

  f32x4 acc[4][4];
#pragma unroll
  for (int i = 0; i < 4; i++)
#pragma unroll
    for (int j = 0; j < 4; j++) acc[i][j] = (f32x4){0.f, 0.f, 0.f, 0.f};

  f16x8 a0[4], l0[4], b0[4], m0[4];  // frag set 0
  f16x8 a1[4], l1[4], b1[4], m1[4];  // frag set 1

  const int nk = k_len / BK;  // 16 or 128 (even)

  // prologue: issue tiles 0,1; wait only for tile 0 (oldest 8 of 16)
  stage(0 * BK, 0);
  stage(1 * BK, 1);
  WAITV8(); SBAR();              // stage(0) done, all waves
  READF(0, a0, l0, b0, m0);
  LGKM0(); SBAR();               // all waves' buf0 reads retired
  stage(2 * BK, 0);              // in flight: stage(1)+stage(2) = 16

  // main: WAITV8|SBAR -> READF(it) | MFMA(it-1) -> LGKM0|SBAR -> stage(it+2)
  int it = 1;
  for (; it + 1 < nk; it += 2) {
    WAITV8(); SBAR();            // stage(it) done (oldest 8 retired)
    READF(1, a1, l1, b1, m1);    // reads(it), it odd -> buf1
    MFMAS(a0, l0, b0, m0);       // MFMA(it-1)
    LGKM0(); SBAR();             // buf1 reads retired everywhere
    if (it + 2 < nk) stage((it + 2) * BK, 1);

    WAITV8(); SBAR();            // stage(it+1) done
    READF(0, a0, l0, b0, m0);    // reads(it+1), even -> buf0
    MFMAS(a1, l1, b1, m1);       // MFMA(it)
    LGKM0(); SBAR();             // buf0 reads retired everywhere
    if (it + 3 < nk) stage((it + 3) * BK, 0);
  }
  // tail: it == nk-1 (odd); only stage(nk-1) can still be in flight
  WAITV0(); SBAR();              // stage(nk-1) done, all waves
  READF(1, a1, l1, b1, m1);      // reads(nk-1)
  MFMAS(a0, l0, b0, m0);         // MFMA(nk-2)
  LGKM0();                       // reads(nk-1) retired (own-wave only needed)
  MFMAS(a1, l1, b1, m1);         // MFMA(nk-1)

  // ---- epilogue: undo 256x W-scale, leaky relu, write next state / output
  const float inv = 1.0f / 256.0f;
#pragma unroll
  for (int i = 0; i < 4; i++) {
#pragma unroll
    for (int j = 0; j < 4; j++) {
#pragma unroll
      for (int e = 0; e < 4; e++) {
        int r = bm + wm * 64 + i * 16 + fq * 4 + e;  // C/D: row=(lane>>4)*4+reg
        int c = bn + wn * 64 + j * 16 + fm;          //      col=lane&15
        float g = acc[i][j][e] * inv;
        float s = (g > 0.0f) ? g : 0.1f * g;
        if (MODE == 0) {
          _Float16 h = (_Float16)s;
          Dh[(size_t)r * NDIM + c] = h;
          Dl[(size_t)r * NDIM + c] = (_Float16)(s - (float)h);
        } else {
          Dout[(size_t)r * NDIM + c] = s;
        }
      }
    }
  }
}

extern "C" void kernel_launch(void* const* d_in, const int* in_sizes, int n_in,
                              void* d_out, int out_size, void* d_ws, size_t ws_size,
                              hipStream_t stream) {
  const float* x = (const float*)d_in[0];  // [2048, 512]
  const float* W = (const float*)d_in[1];  // [4096, 4096]
  float* out = (float*)d_out;              // [2048, 4096]
  char* ws = (char*)d_ws;

  const size_t WT_BYTES = (size_t)NDIM * NDIM * 2;  // 32 MB each
  const size_t S_BYTES = (size_t)BATCH * NDIM * 2;  // 16 MB each
  _Float16* Wth = (_Float16*)ws;
  _Float16* Wtl = (_Float16*)(ws + WT_BYTES);
  _Float16* SAh = (_Float16*)(ws + 2 * WT_BYTES);
  _Float16* SAl = (_Float16*)(ws + 2 * WT_BYTES + S_BYTES);
  _Float16* SBh = (_Float16*)(ws + 2 * WT_BYTES + 2 * S_BYTES);
  _Float16* SBl = (_Float16*)(ws + 2 * WT_BYTES + 3 * S_BYTES);

  prep_x<<<(BATCH * NDIM) / 256, 256, 0, stream>>>(x, SAh, SAl);
  prep_w<<<dim3(NDIM / 32, NDIM / 32), dim3(32, 8), 0, stream>>>(W, Wth, Wtl);

  dim3 grid((NDIM / BN) * (BATCH / BM));  // 512 linear, swizzled in-kernel
  for (int t = 1; t <= 16; t++) {
    const _Float16* ah = (t & 1) ? SAh : SBh;
    const _Float16* al = (t & 1) ? SAl : SBl;
    _Float16* dh = (t & 1) ? SBh : SAh;
    _Float16* dl = (t & 1) ? SBl : SAl;
    int klen = (t == 1) ? INDIM : NDIM;
    if (t < 16)
      step_kernel<0><<<grid, 256, 0, stream>>>(ah, al, Wth, Wtl, dh, dl, nullptr, klen);
    else
      step_kernel<1><<<grid, 256, 0, stream>>>(ah, al, Wth, Wtl, nullptr, nullptr, out, klen);
  }
}